// Round 5
// baseline (185.218 us; speedup 1.0000x reference)
//
#include <hip/hip_runtime.h>

// YOLOv3 loss: B=32, A=3, S=52, C=80
constexpr int Aa = 3, Ss = 52, Cc = 80;
constexpr int NCELL = 32 * Aa * Ss * Ss;                 // 259584
constexpr int PSTR  = 5 + Cc;                            // 85 floats per cell
constexpr unsigned NP4 = (unsigned)NCELL * 85u / 4u;     // 5,516,160 float4s (exact)
constexpr float L_CLASS = 1.0f, L_NOOBJ = 10.0f, L_OBJ = 1.0f, L_BOX = 10.0f;

// ws layout (floats): [0]=n_obj [1]=n_noobj [2]=noobj_sum [3]=obj_sum [4]=box_sum [5]=cls_sum

__device__ __forceinline__ float bce0(float x) {         // bce(x, 0)
    return fmaxf(x, 0.0f) + log1pf(expf(-fabsf(x)));
}

// Process one float4 of the prediction stream. Must be called with the FULL
// wave active (use `in` to predicate tail lanes) so ballot/shfl are defined.
__device__ __forceinline__ void process_f4(float4 u, unsigned f0, bool in,
                                           const float* __restrict__ pred,
                                           const float* __restrict__ tgt,
                                           const float* __restrict__ anchors,
                                           int lane,
                                           float& a_nob, float& a_nn, float& a_no,
                                           float& a_obj, float& a_box, float& a_cls) {
    const unsigned cell = f0 / 85u;                      // magic-mul
    const unsigned r    = f0 - cell * 85u;
    // exactly one float4 per cell contains that cell's p0 (r in {0,84,83,82})
    const bool hit = in && ((r == 0u) || (r >= 82u));
    const float p0 = (r == 0u) ? u.x : ((r == 84u) ? u.y : ((r == 83u) ? u.z : u.w));
    const unsigned oc = cell + ((r != 0u) ? 1u : 0u);

    float t0 = -1.0f;
    if (hit) t0 = tgt[(size_t)oc * 6u];                  // predicated gather (~3 lanes/wave)

    const bool noobj = hit && (t0 == 0.0f);
    const float b = bce0(p0);                            // all lanes; same issue cost as masked
    a_nn += noobj ? 1.0f : 0.0f;
    a_no += noobj ? b : 0.0f;

    // --- object cells: wave-cooperative, ~6% of wave-iterations enter ---
    unsigned long long m = __ballot(hit && (t0 == 1.0f));
    while (m) {                                          // wave-uniform loop
        const int src = __ffsll(m) - 1;
        m &= m - 1;
        const int socell = __shfl((int)oc, src, 64);
        const float sp0  = __shfl(p0, src, 64);
        const float* row = pred + (size_t)socell * 85u;
        const float* t   = tgt + (size_t)socell * 6u;

        // 80 logits: lane -> c=lane; lanes 0..15 also -> c=64+lane (L2-hot)
        float v0 = row[5 + lane];
        float v1 = (lane < 16) ? row[69 + lane] : -INFINITY;
        float mx = fmaxf(v0, v1);
        #pragma unroll
        for (int off = 32; off; off >>= 1) mx = fmaxf(mx, __shfl_xor(mx, off, 64));
        float e = expf(v0 - mx) + ((lane < 16) ? expf(v1 - mx) : 0.0f);
        #pragma unroll
        for (int off = 32; off; off >>= 1) e += __shfl_xor(e, off, 64);

        const int cls = (int)t[5];                       // wave-uniform broadcast load
        const float lc = (cls < 64) ? __shfl(v0, cls, 64) : __shfl(v1, cls - 64, 64);

        // wave-uniform box decode + IOU (all lanes compute; cheap)
        const float px = row[1], py = row[2], pw = row[3], ph = row[4];
        const float tx = t[1], ty = t[2], tw = t[3], th = t[4];
        const unsigned a = ((unsigned)socell / (unsigned)(Ss * Ss)) % (unsigned)Aa;
        const float ax = anchors[2 * a], ay = anchors[2 * a + 1];

        const float sx = 1.0f / (1.0f + expf(-px));
        const float sy = 1.0f / (1.0f + expf(-py));
        const float ew = expf(pw) * ax;
        const float eh = expf(ph) * ay;

        const float ax1 = sx - ew * 0.5f, ax2 = sx + ew * 0.5f;
        const float ay1 = sy - eh * 0.5f, ay2 = sy + eh * 0.5f;
        const float bx1 = tx - tw * 0.5f, bx2 = tx + tw * 0.5f;
        const float by1 = ty - th * 0.5f, by2 = ty + th * 0.5f;
        const float iw = fmaxf(fminf(ax2, bx2) - fmaxf(ax1, bx1), 0.0f);
        const float ih = fmaxf(fminf(ay2, by2) - fmaxf(ay1, by1), 0.0f);
        const float inter = iw * ih;
        const float area_a = fabsf((ax2 - ax1) * (ay2 - ay1));
        const float area_b = fabsf((bx2 - bx1) * (by2 - by1));
        const float iou = inter / (area_a + area_b - inter + 1e-6f);

        if (lane == src) {
            a_nob += 1.0f;
            a_cls += (mx + logf(e)) - lc;
            a_obj += fmaxf(sp0, 0.0f) - sp0 * iou + log1pf(expf(-fabsf(sp0)));
            const float dx = sx - tx, dy = sy - ty;
            const float dw = pw - logf(tw / ax + 1e-16f);
            const float dh = ph - logf(th / ay + 1e-16f);
            a_box += dx * dx + dy * dy + dw * dw + dh * dh;
        }
    }
}

__global__ void __launch_bounds__(256) yolo_fused(const float4* __restrict__ pred4,
                                                  const float* __restrict__ pred,
                                                  const float* __restrict__ tgt,
                                                  const float* __restrict__ anchors,
                                                  float* __restrict__ acc) {
    const int lane = threadIdx.x & 63;
    const unsigned stride = gridDim.x * blockDim.x;
    const unsigned tid = blockIdx.x * blockDim.x + threadIdx.x;

    float a_nob = 0.f, a_nn = 0.f, a_no = 0.f, a_obj = 0.f, a_box = 0.f, a_cls = 0.f;

    unsigned j  = tid;
    unsigned wb = tid - lane;   // wave-uniform base

    // quad-unrolled main loop: all 4 loads in flight, all lanes in-bounds
    for (; wb + 3u * stride + 63u < NP4; j += 4u * stride, wb += 4u * stride) {
        float4 u0 = pred4[j];
        float4 u1 = pred4[j + stride];
        float4 u2 = pred4[j + 2u * stride];
        float4 u3 = pred4[j + 3u * stride];
        process_f4(u0, 4u * j, true, pred, tgt, anchors, lane, a_nob, a_nn, a_no, a_obj, a_box, a_cls);
        process_f4(u1, 4u * (j + stride), true, pred, tgt, anchors, lane, a_nob, a_nn, a_no, a_obj, a_box, a_cls);
        process_f4(u2, 4u * (j + 2u * stride), true, pred, tgt, anchors, lane, a_nob, a_nn, a_no, a_obj, a_box, a_cls);
        process_f4(u3, 4u * (j + 3u * stride), true, pred, tgt, anchors, lane, a_nob, a_nn, a_no, a_obj, a_box, a_cls);
    }
    // wave-uniform remainder: full wave active, per-lane predication
    for (; wb < NP4; j += stride, wb += stride) {
        const bool in = (j < NP4);
        float4 u = make_float4(0.f, 0.f, 0.f, 0.f);
        if (in) u = pred4[j];
        process_f4(u, 4u * j, in, pred, tgt, anchors, lane, a_nob, a_nn, a_no, a_obj, a_box, a_cls);
    }

    // wave shuffle reduce -> LDS -> 6 fire-and-forget atomics per block
    #pragma unroll
    for (int off = 32; off > 0; off >>= 1) {
        a_nob += __shfl_down(a_nob, off, 64);
        a_nn  += __shfl_down(a_nn, off, 64);
        a_no  += __shfl_down(a_no, off, 64);
        a_obj += __shfl_down(a_obj, off, 64);
        a_box += __shfl_down(a_box, off, 64);
        a_cls += __shfl_down(a_cls, off, 64);
    }
    __shared__ float sdata[6][4];
    const int wid = threadIdx.x >> 6;
    if (lane == 0) {
        sdata[0][wid] = a_nob; sdata[1][wid] = a_nn;  sdata[2][wid] = a_no;
        sdata[3][wid] = a_obj; sdata[4][wid] = a_box; sdata[5][wid] = a_cls;
    }
    __syncthreads();
    if (threadIdx.x == 0) {
        float v0 = 0, v1 = 0, v2 = 0, v3 = 0, v4 = 0, v5 = 0;
        for (int w = 0; w < 4; ++w) {
            v0 += sdata[0][w]; v1 += sdata[1][w]; v2 += sdata[2][w];
            v3 += sdata[3][w]; v4 += sdata[4][w]; v5 += sdata[5][w];
        }
        atomicAdd(&acc[0], v0);
        atomicAdd(&acc[1], v1);
        atomicAdd(&acc[2], v2);
        atomicAdd(&acc[3], v3);
        atomicAdd(&acc[4], v4);
        atomicAdd(&acc[5], v5);
    }
}

__global__ void yolo_final(const float* __restrict__ acc, float* __restrict__ out) {
    const float n_obj   = fmaxf(acc[0], 1.0f);
    const float n_noobj = fmaxf(acc[1], 1.0f);
    out[0] = L_NOOBJ * acc[2] / n_noobj
           + L_OBJ   * acc[3] / n_obj
           + L_BOX   * acc[4] / (n_obj * 4.0f)
           + L_CLASS * acc[5] / n_obj;
}

extern "C" void kernel_launch(void* const* d_in, const int* in_sizes, int n_in,
                              void* d_out, int out_size, void* d_ws, size_t ws_size,
                              hipStream_t stream) {
    const float* pred = (const float*)d_in[0];
    const float* tgt  = (const float*)d_in[1];
    const float* anc  = (const float*)d_in[2];
    float* out = (float*)d_out;
    float* acc = (float*)d_ws;

    hipMemsetAsync(acc, 0, 6 * sizeof(float), stream);

    yolo_fused<<<2048, 256, 0, stream>>>((const float4*)pred, pred, tgt, anc, acc);
    yolo_final<<<1, 1, 0, stream>>>(acc, out);
}

// Round 6
// 132.375 us; speedup vs baseline: 1.3992x; 1.3992x over previous
//
#include <hip/hip_runtime.h>

// YOLOv3 loss: B=32, A=3, S=52, C=80
constexpr int Aa = 3, Ss = 52, Cc = 80;
constexpr int NCELL = 32 * Aa * Ss * Ss;                 // 259584 = 1014 * 256
constexpr unsigned NP4 = (unsigned)NCELL * 85u / 4u;     // 5,516,160 float4s (exact)
constexpr float L_CLASS = 1.0f, L_NOOBJ = 10.0f, L_OBJ = 1.0f, L_BOX = 10.0f;

// ws layout: [0..5] float accs: 0=n_obj 1=n_noobj 2=noobj_sum 3=obj_sum 4=box_sum 5=cls_sum
// byte 32.. : class map, 1 byte per cell (0=noobj, 1=obj, 2=neither)

__device__ __forceinline__ float bce0(float x) {         // bce(x, 0)
    return fmaxf(x, 0.0f) + log1pf(expf(-fabsf(x)));
}

// --- K1: build class map + handle object cells (wave-cooperative) ---
__global__ void __launch_bounds__(256) yolo_map_obj(const float* __restrict__ pred,
                                                    const float* __restrict__ tgt,
                                                    const float* __restrict__ anchors,
                                                    unsigned char* __restrict__ map,
                                                    float* __restrict__ acc) {
    const int lane = threadIdx.x & 63;
    const int cell = blockIdx.x * blockDim.x + threadIdx.x;   // grid exactly covers NCELL

    const float t0 = tgt[(size_t)cell * 6u];                  // 64 consecutive cells/wave
    const bool is_obj = (t0 == 1.0f);
    map[cell] = is_obj ? (unsigned char)1 : (t0 == 0.0f ? (unsigned char)0 : (unsigned char)2);

    float a_nob = 0.f, a_obj = 0.f, a_box = 0.f, a_cls = 0.f;

    unsigned long long m = __ballot(is_obj);
    while (m) {                                               // wave-uniform
        const int src = __ffsll(m) - 1;
        m &= m - 1;
        const int socell = __shfl(cell, src, 64);
        const float* row = pred + (size_t)socell * 85u;
        const float* t   = tgt + (size_t)socell * 6u;

        // 80 logits cooperative: lane -> c=lane; lanes 0..15 also -> c=64+lane
        float v0 = row[5 + lane];
        float v1 = (lane < 16) ? row[69 + lane] : -INFINITY;
        float mx = fmaxf(v0, v1);
        #pragma unroll
        for (int off = 32; off; off >>= 1) mx = fmaxf(mx, __shfl_xor(mx, off, 64));
        float e = expf(v0 - mx) + ((lane < 16) ? expf(v1 - mx) : 0.0f);
        #pragma unroll
        for (int off = 32; off; off >>= 1) e += __shfl_xor(e, off, 64);

        const int cls = (int)t[5];                            // wave-uniform broadcast
        const float lc = (cls < 64) ? __shfl(v0, cls, 64) : __shfl(v1, cls - 64, 64);

        const float p0 = row[0], px = row[1], py = row[2], pw = row[3], ph = row[4];
        const float tx = t[1], ty = t[2], tw = t[3], th = t[4];
        const unsigned a = ((unsigned)socell / (unsigned)(Ss * Ss)) % (unsigned)Aa;
        const float ax = anchors[2 * a], ay = anchors[2 * a + 1];

        const float sx = 1.0f / (1.0f + expf(-px));
        const float sy = 1.0f / (1.0f + expf(-py));
        const float ew = expf(pw) * ax;
        const float eh = expf(ph) * ay;

        const float ax1 = sx - ew * 0.5f, ax2 = sx + ew * 0.5f;
        const float ay1 = sy - eh * 0.5f, ay2 = sy + eh * 0.5f;
        const float bx1 = tx - tw * 0.5f, bx2 = tx + tw * 0.5f;
        const float by1 = ty - th * 0.5f, by2 = ty + th * 0.5f;
        const float iw = fmaxf(fminf(ax2, bx2) - fmaxf(ax1, bx1), 0.0f);
        const float ih = fmaxf(fminf(ay2, by2) - fmaxf(ay1, by1), 0.0f);
        const float inter = iw * ih;
        const float area_a = fabsf((ax2 - ax1) * (ay2 - ay1));
        const float area_b = fabsf((bx2 - bx1) * (by2 - by1));
        const float iou = inter / (area_a + area_b - inter + 1e-6f);

        if (lane == src) {
            a_nob += 1.0f;
            a_cls += (mx + logf(e)) - lc;
            a_obj += fmaxf(p0, 0.0f) - p0 * iou + log1pf(expf(-fabsf(p0)));
            const float dx = sx - tx, dy = sy - ty;
            const float dw = pw - logf(tw / ax + 1e-16f);
            const float dh = ph - logf(th / ay + 1e-16f);
            a_box += dx * dx + dy * dy + dw * dw + dh * dh;
        }
    }

    // wave reduce -> LDS -> 4 fire-and-forget atomics per block
    #pragma unroll
    for (int off = 32; off > 0; off >>= 1) {
        a_nob += __shfl_down(a_nob, off, 64);
        a_obj += __shfl_down(a_obj, off, 64);
        a_box += __shfl_down(a_box, off, 64);
        a_cls += __shfl_down(a_cls, off, 64);
    }
    __shared__ float sdata[4][4];
    const int wid = threadIdx.x >> 6;
    if (lane == 0) {
        sdata[0][wid] = a_nob; sdata[1][wid] = a_obj;
        sdata[2][wid] = a_box; sdata[3][wid] = a_cls;
    }
    __syncthreads();
    if (threadIdx.x == 0) {
        float v0 = 0, v1 = 0, v2 = 0, v3 = 0;
        for (int w = 0; w < 4; ++w) {
            v0 += sdata[0][w]; v1 += sdata[1][w]; v2 += sdata[2][w]; v3 += sdata[3][w];
        }
        atomicAdd(&acc[0], v0);
        atomicAdd(&acc[3], v1);
        atomicAdd(&acc[4], v2);
        atomicAdd(&acc[5], v3);
    }
}

// --- K2: pure coalesced stream over predictions; map byte (L2-hot) gates noobj BCE ---
__device__ __forceinline__ void proc_f4(float4 u, unsigned f0,
                                        const unsigned char* __restrict__ map,
                                        float& a_nn, float& a_no) {
    const unsigned cell = f0 / 85u;                  // magic-mul
    const unsigned r    = f0 - cell * 85u;
    if ((r == 0u) || (r >= 82u)) {                   // this float4 holds a cell's p0
        const unsigned oc = cell + ((r != 0u) ? 1u : 0u);
        const float p0 = (r == 0u) ? u.x : ((r == 84u) ? u.y : ((r == 83u) ? u.z : u.w));
        if (map[oc] == 0) {                          // 1-byte L2-resident lookup
            a_nn += 1.0f;
            a_no += bce0(p0);
        }
    }
}

__global__ void __launch_bounds__(256) yolo_noobj(const float4* __restrict__ pred4,
                                                  const unsigned char* __restrict__ map,
                                                  float* __restrict__ acc) {
    float a_nn = 0.f, a_no = 0.f;
    const unsigned stride = gridDim.x * blockDim.x;
    unsigned j = blockIdx.x * blockDim.x + threadIdx.x;

    // 4-deep unrolled stream: all 4 loads independent and in flight
    for (; j + 3u * stride < NP4; j += 4u * stride) {
        float4 u0 = pred4[j];
        float4 u1 = pred4[j + stride];
        float4 u2 = pred4[j + 2u * stride];
        float4 u3 = pred4[j + 3u * stride];
        proc_f4(u0, 4u * j, map, a_nn, a_no);
        proc_f4(u1, 4u * (j + stride), map, a_nn, a_no);
        proc_f4(u2, 4u * (j + 2u * stride), map, a_nn, a_no);
        proc_f4(u3, 4u * (j + 3u * stride), map, a_nn, a_no);
    }
    for (; j < NP4; j += stride) {                   // thread-local tail, no wave ops
        proc_f4(pred4[j], 4u * j, map, a_nn, a_no);
    }

    #pragma unroll
    for (int off = 32; off > 0; off >>= 1) {
        a_nn += __shfl_down(a_nn, off, 64);
        a_no += __shfl_down(a_no, off, 64);
    }
    __shared__ float sdata[2][4];
    const int lane = threadIdx.x & 63, wid = threadIdx.x >> 6;
    if (lane == 0) { sdata[0][wid] = a_nn; sdata[1][wid] = a_no; }
    __syncthreads();
    if (threadIdx.x == 0) {
        float s0 = 0.f, s1 = 0.f;
        for (int w = 0; w < 4; ++w) { s0 += sdata[0][w]; s1 += sdata[1][w]; }
        atomicAdd(&acc[1], s0);
        atomicAdd(&acc[2], s1);
    }
}

__global__ void yolo_final(const float* __restrict__ acc, float* __restrict__ out) {
    const float n_obj   = fmaxf(acc[0], 1.0f);
    const float n_noobj = fmaxf(acc[1], 1.0f);
    out[0] = L_NOOBJ * acc[2] / n_noobj
           + L_OBJ   * acc[3] / n_obj
           + L_BOX   * acc[4] / (n_obj * 4.0f)
           + L_CLASS * acc[5] / n_obj;
}

extern "C" void kernel_launch(void* const* d_in, const int* in_sizes, int n_in,
                              void* d_out, int out_size, void* d_ws, size_t ws_size,
                              hipStream_t stream) {
    const float* pred = (const float*)d_in[0];
    const float* tgt  = (const float*)d_in[1];
    const float* anc  = (const float*)d_in[2];
    float* out = (float*)d_out;
    float* acc = (float*)d_ws;
    unsigned char* map = (unsigned char*)d_ws + 32;   // NCELL bytes (260 KB)

    hipMemsetAsync(acc, 0, 32, stream);

    yolo_map_obj<<<NCELL / 256, 256, 0, stream>>>(pred, tgt, anc, map, acc);
    yolo_noobj<<<2048, 256, 0, stream>>>((const float4*)pred, map, acc);
    yolo_final<<<1, 1, 0, stream>>>(acc, out);
}

// Round 7
// 40.819 us; speedup vs baseline: 4.5376x; 3.2430x over previous
//
#include <hip/hip_runtime.h>

// YOLOv3 loss: B=32, A=3, S=52, C=80
constexpr int Aa = 3, Ss = 52, Cc = 80;
constexpr int NCELL = 32 * Aa * Ss * Ss;       // 259584 (divisible by 4)
constexpr int PSTR  = 5 + Cc;                  // 85 floats per cell
constexpr int G     = 4;                       // cells per thread
constexpr float L_CLASS = 1.0f, L_NOOBJ = 10.0f, L_OBJ = 1.0f, L_BOX = 10.0f;

// ---- DPP helpers: row_ror:k butterfly within 16-lane rows (all lanes valid) ----
__device__ __forceinline__ float dpp_ror1(float x) {
    return __builtin_bit_cast(float, __builtin_amdgcn_update_dpp(
        0, __builtin_bit_cast(int, x), 0x121, 0xf, 0xf, false));
}
__device__ __forceinline__ float dpp_ror2(float x) {
    return __builtin_bit_cast(float, __builtin_amdgcn_update_dpp(
        0, __builtin_bit_cast(int, x), 0x122, 0xf, 0xf, false));
}
__device__ __forceinline__ float dpp_ror4(float x) {
    return __builtin_bit_cast(float, __builtin_amdgcn_update_dpp(
        0, __builtin_bit_cast(int, x), 0x124, 0xf, 0xf, false));
}
__device__ __forceinline__ float dpp_ror8(float x) {
    return __builtin_bit_cast(float, __builtin_amdgcn_update_dpp(
        0, __builtin_bit_cast(int, x), 0x128, 0xf, 0xf, false));
}
// full 64-lane reduce, result in all lanes: 4 DPP ops + 2 DS shuffles
__device__ __forceinline__ float wave_sum(float x) {
    x += dpp_ror1(x); x += dpp_ror2(x); x += dpp_ror4(x); x += dpp_ror8(x);
    x += __shfl_xor(x, 16, 64);
    x += __shfl_xor(x, 32, 64);
    return x;
}
__device__ __forceinline__ float wave_max(float x) {
    x = fmaxf(x, dpp_ror1(x)); x = fmaxf(x, dpp_ror2(x));
    x = fmaxf(x, dpp_ror4(x)); x = fmaxf(x, dpp_ror8(x));
    x = fmaxf(x, __shfl_xor(x, 16, 64));
    x = fmaxf(x, __shfl_xor(x, 32, 64));
    return x;
}
__device__ __forceinline__ float rdlane(float v, int l) {
    return __builtin_bit_cast(float, __builtin_amdgcn_readlane(__builtin_bit_cast(int, v), l));
}

__device__ __forceinline__ float bce0_fast(float x) {   // bce(x,0) = max(x,0)+log(1+exp(-|x|))
    return fmaxf(x, 0.0f) + __logf(1.0f + __expf(-fabsf(x)));
}

// acc layout: [0]=n_obj [1]=n_noobj [2]=noobj_sum [3]=obj_sum [4]=box_sum [5]=cls_sum
__global__ void __launch_bounds__(256) yolo_main(const float* __restrict__ pred,
                                                 const float* __restrict__ tgt,
                                                 const float* __restrict__ anchors,
                                                 float* __restrict__ acc) {
    const int lane = threadIdx.x & 63;
    const int tid  = blockIdx.x * blockDim.x + threadIdx.x;
    const int base = tid * G;
    const bool valid = base < NCELL;   // NCELL % 4 == 0 => valid implies all 4 cells valid

    float a_nobj = 0.f, a_nnoobj = 0.f, a_noobj = 0.f, a_obj = 0.f, a_box = 0.f, a_cls = 0.f;

    // --- issue all loads up front (ILP); p0 gathers (worst latency) first ---
    float p0[G];       // 4 independent stride-340B gathers
    float tf[6 * G];   // 4 cells x 6 target floats via 6 aligned float4 loads
    if (valid) {
        #pragma unroll
        for (int g = 0; g < G; ++g) p0[g] = pred[(size_t)(base + g) * PSTR];
        const float4* tp = reinterpret_cast<const float4*>(tgt + (size_t)base * 6);
        #pragma unroll
        for (int i = 0; i < 6; ++i) {
            float4 v = tp[i];
            tf[4 * i] = v.x; tf[4 * i + 1] = v.y; tf[4 * i + 2] = v.z; tf[4 * i + 3] = v.w;
        }
    }

    #pragma unroll
    for (int g = 0; g < G; ++g) {
        const int cell = base + g;
        const float t0  = valid ? tf[g * 6] : -1.0f;   // -1 => neither obj nor noobj
        const float p0g = valid ? p0[g] : 0.0f;
        const bool is_obj = (t0 == 1.0f);

        if (t0 == 0.0f) {
            a_nnoobj += 1.0f;
            a_noobj  += bce0_fast(p0g);
        }

        int clsg = 0;
        if (is_obj) {
            a_nobj += 1.0f;
            const float* p = pred + (size_t)cell * PSTR;
            const int a = (cell / (Ss * Ss)) % Aa;
            const float ax = anchors[2 * a], ay = anchors[2 * a + 1];

            float px = p[1], py = p[2], pw = p[3], ph = p[4];
            float tx = tf[g * 6 + 1], ty = tf[g * 6 + 2];
            float tw = tf[g * 6 + 3], th = tf[g * 6 + 4];

            float sx = 1.0f / (1.0f + __expf(-px));
            float sy = 1.0f / (1.0f + __expf(-py));
            float ew = __expf(pw) * ax;
            float eh = __expf(ph) * ay;

            float ax1 = sx - ew * 0.5f, ax2 = sx + ew * 0.5f;
            float ay1 = sy - eh * 0.5f, ay2 = sy + eh * 0.5f;
            float bx1 = tx - tw * 0.5f, bx2 = tx + tw * 0.5f;
            float by1 = ty - th * 0.5f, by2 = ty + th * 0.5f;
            float iw = fmaxf(fminf(ax2, bx2) - fmaxf(ax1, bx1), 0.0f);
            float ih = fmaxf(fminf(ay2, by2) - fmaxf(ay1, by1), 0.0f);
            float inter = iw * ih;
            float area_a = fabsf((ax2 - ax1) * (ay2 - ay1));
            float area_b = fabsf((bx2 - bx1) * (by2 - by1));
            float iou = inter / (area_a + area_b - inter + 1e-6f);

            a_obj += fmaxf(p0g, 0.0f) - p0g * iou + __logf(1.0f + __expf(-fabsf(p0g)));

            float dx = sx - tx, dy = sy - ty;
            float dw = pw - __logf(tw / ax + 1e-16f);
            float dh = ph - __logf(th / ay + 1e-16f);
            a_box += dx * dx + dy * dy + dw * dw + dh * dh;

            clsg = (int)tf[g * 6 + 5];
        }

        // --- wave-parallel class CE: all 64 lanes cooperate per object cell ---
        unsigned long long m = __ballot(is_obj);
        while (m) {                                   // wave-uniform loop
            const int src = __ffsll(m) - 1;           // uniform
            m &= m - 1;
            const int ocell = __builtin_amdgcn_readlane(cell, src);
            const int ocls  = __builtin_amdgcn_readlane(clsg, src);
            const float* row = pred + (size_t)ocell * PSTR + 5;
            // 80 contiguous logits: lane reads idx lane; lanes 0-15 also read 64+lane
            float v0 = row[lane];
            float v1 = (lane < 16) ? row[64 + lane] : -INFINITY;
            float mx = wave_max(fmaxf(v0, v1));
            float e  = wave_sum(__expf(v0 - mx) + ((lane < 16) ? __expf(v1 - mx) : 0.0f));
            float lc = (ocls < 64) ? rdlane(v0, ocls) : rdlane(v1, ocls - 64);
            if (lane == src) a_cls += (mx + __logf(e)) - lc;
        }
    }

    // --- wave reduce (DPP+xor) -> LDS -> 1 atomic per block per accumulator ---
    a_nobj   = wave_sum(a_nobj);
    a_nnoobj = wave_sum(a_nnoobj);
    a_noobj  = wave_sum(a_noobj);
    a_obj    = wave_sum(a_obj);
    a_box    = wave_sum(a_box);
    a_cls    = wave_sum(a_cls);

    __shared__ float sdata[6][4];
    const int wid = threadIdx.x >> 6;
    if (lane == 0) {
        sdata[0][wid] = a_nobj;
        sdata[1][wid] = a_nnoobj;
        sdata[2][wid] = a_noobj;
        sdata[3][wid] = a_obj;
        sdata[4][wid] = a_box;
        sdata[5][wid] = a_cls;
    }
    __syncthreads();
    if (threadIdx.x == 0) {
        float v0 = 0, v1 = 0, v2 = 0, v3 = 0, v4 = 0, v5 = 0;
        for (int w = 0; w < 4; ++w) {
            v0 += sdata[0][w]; v1 += sdata[1][w]; v2 += sdata[2][w];
            v3 += sdata[3][w]; v4 += sdata[4][w]; v5 += sdata[5][w];
        }
        atomicAdd(&acc[0], v0);
        atomicAdd(&acc[1], v1);
        atomicAdd(&acc[2], v2);
        atomicAdd(&acc[3], v3);
        atomicAdd(&acc[4], v4);
        atomicAdd(&acc[5], v5);
    }
}

__global__ void yolo_final(const float* __restrict__ acc, float* __restrict__ out) {
    const float n_obj   = fmaxf(acc[0], 1.0f);
    const float n_noobj = fmaxf(acc[1], 1.0f);
    out[0] = L_NOOBJ * acc[2] / n_noobj
           + L_OBJ   * acc[3] / n_obj
           + L_BOX   * acc[4] / (n_obj * 4.0f)
           + L_CLASS * acc[5] / n_obj;
}

extern "C" void kernel_launch(void* const* d_in, const int* in_sizes, int n_in,
                              void* d_out, int out_size, void* d_ws, size_t ws_size,
                              hipStream_t stream) {
    const float* pred = (const float*)d_in[0];
    const float* tgt  = (const float*)d_in[1];
    const float* anc  = (const float*)d_in[2];
    float* out = (float*)d_out;
    float* acc = (float*)d_ws;

    hipMemsetAsync(acc, 0, 6 * sizeof(float), stream);

    const int block = 256;
    const int nthreads = NCELL / G;                      // 64896
    const int grid = (nthreads + block - 1) / block;     // 254 blocks
    yolo_main<<<grid, block, 0, stream>>>(pred, tgt, anc, acc);
    yolo_final<<<1, 1, 0, stream>>>(acc, out);
}